// Round 17
// baseline (302.247 us; speedup 1.0000x reference)
//
#include <hip/hip_runtime.h>
#include <math.h>

#define BATCH 32768
#define TOBS  20
#define TPRED 12

typedef _Float16 f16;
typedef f16  half8 __attribute__((ext_vector_type(8)));
typedef float f32x4 __attribute__((ext_vector_type(4)));

#define LOG2E 1.44269504088896f
#define K2    2.88539008177793f   // 2*log2(e)

// ---------------- d_ws layout (bytes) ----------------
// Gate-grouped A-fragment packing (rt-contiguous j), EXP2-PRESCALED:
//   packed row r' = rt*16 + m  represents original row (m&3)*64 + (m>>2)*16 + rt
//   (lane quad Q's 4 acc regs = gates i,f,g,o of hidden unit j = Q*16 + rt)
//   Sigmoid-gate rows (i,f,o) scaled by log2e, g-gate rows by 2*log2e.
//   frag f16 index = ((rt*KT + kt)*64 + lane)*8 + i
#define OFF_W0A  0u        // L0:  [Whh0 kt0,1 | aug-compact]  32768 + 4096 = 36864 B
#define OFF_WDA  36864u    // dec: same structure              36864 B
#define OFF_W1   73728u    // L1 cat [Wih1|Whh1], KT=4         65536 B
#define OFF_B1   139264u   // bias1 gate-grouped f32[256]      1024 B (prescaled)
#define OFF_OUT  140288u   // out-proj frags KT=3 (UNSCALED)   3072 B
#define WS_NEED  ((size_t)143360)

__device__ __forceinline__ float frcp(float x){
#if __has_builtin(__builtin_amdgcn_rcpf)
  return __builtin_amdgcn_rcpf(x);
#else
  return 1.0f/x;
#endif
}
__device__ __forceinline__ float fexp2(float x){
#if __has_builtin(__builtin_amdgcn_exp2f)
  return __builtin_amdgcn_exp2f(x);
#else
  return exp2f(x);
#endif
}
__device__ __forceinline__ f32x4 MFMA(half8 a, half8 b, f32x4 c){
  return __builtin_amdgcn_mfma_f32_16x16x32_f16(a, b, c, 0, 0, 0);
}
__device__ __forceinline__ int grow(int rt, int m){  // gate-grouped original row
  return (m&3)*64 + (m>>2)*16 + rt;
}
__device__ __forceinline__ float gsc(int m){         // per-row exp2 prescale
  return ((m&3)==2) ? (2.0f*LOG2E) : LOG2E;
}

// Merged-rcp gate math: 5 exp2 + 3 rcp.
__device__ __forceinline__ float gate_h(const f32x4 a, float& c){
  const float ei = fexp2(-a[0]);
  const float ef = fexp2(-a[1]);
  const float eg = fexp2(-a[2]);
  const float eo = fexp2(-a[3]);
  const float fg  = frcp(1.0f + ef);
  const float rig = frcp((1.0f + ei)*(1.0f + eg));
  const float cn  = fg*c + (1.0f - eg)*rig;
  c = cn;
  const float ec = fexp2(cn * -K2);
  return (1.0f - ec) * frcp((1.0f + eo)*(1.0f + ec));
}

// ---------------- weight packing ----------------
__global__ void prep_pack(const float* __restrict__ wih0, const float* __restrict__ whh0,
                          const float* __restrict__ bih0, const float* __restrict__ bhh0,
                          const float* __restrict__ wih1, const float* __restrict__ whh1,
                          const float* __restrict__ bih1, const float* __restrict__ bhh1,
                          const float* __restrict__ dwih, const float* __restrict__ dwhh,
                          const float* __restrict__ dbih, const float* __restrict__ dbhh,
                          const float* __restrict__ outw, const float* __restrict__ outb,
                          char* __restrict__ ws)
{
  const int tid = blockIdx.x*blockDim.x + threadIdx.x;
  const int stride = gridDim.x*blockDim.x;

  f16* w0 = (f16*)(ws + OFF_W0A);
  f16* wd = (f16*)(ws + OFF_WDA);
  // hh frags (kt=0,1), prescaled
  for (int idx = tid; idx < 16384; idx += stride) {
    int i = idx & 7, lane = (idx>>3)&63, kt = (idx>>9)&1, rt = idx>>10;
    int m = lane&15;
    int row = grow(rt, m);
    int k   = kt*32 + (lane>>4)*8 + i;
    float s = gsc(m);
    w0[idx] = (f16)(whh0[row*64 + k]*s);
    wd[idx] = (f16)(dwhh[row*64 + k]*s);
  }
  // aug-compact (quad0 data only): [rt][m][8]: i=0->wih[:,0], 1->wih[:,1], 2->bias
  for (int idx = tid; idx < 2048; idx += stride) {
    int i = idx & 7, m = (idx>>3)&15, rt = idx>>7;
    int row = grow(rt, m);
    float s = gsc(m);
    float v0 = (i==0) ? wih0[row*2] : (i==1) ? wih0[row*2+1] : (i==2) ? (bih0[row]+bhh0[row]) : 0.f;
    float vd = (i==0) ? dwih[row*2] : (i==1) ? dwih[row*2+1] : (i==2) ? (dbih[row]+dbhh[row]) : 0.f;
    w0[16384 + idx] = (f16)(v0*s);
    wd[16384 + idx] = (f16)(vd*s);
  }
  // L1 cat pack, KT=4: k<64 -> Wih1, else Whh1 (prescaled)
  f16* w1 = (f16*)(ws + OFF_W1);
  for (int idx = tid; idx < 32768; idx += stride) {
    int i = idx & 7, lane = (idx>>3)&63, kt = (idx>>9)&3, rt = idx>>11;
    int m = lane&15;
    int row = grow(rt, m);
    int k   = kt*32 + (lane>>4)*8 + i;
    float s = gsc(m);
    w1[idx] = (f16)(((k < 64) ? wih1[row*64 + k] : whh1[row*64 + (k-64)])*s);
  }
  // bias1 gate-grouped, prescaled
  float* b1 = (float*)(ws + OFF_B1);
  for (int idx = tid; idx < 256; idx += stride) {
    int m = idx & 15, rt = idx >> 4;
    int row = grow(rt, m);
    b1[idx] = (bih1[row] + bhh1[row])*gsc(m);
  }
  // out-proj frags KT=3 (plain rows 0,1; k=64 -> out_b) -- UNSCALED
  f16* wo = (f16*)(ws + OFF_OUT);
  for (int idx = tid; idx < 1536; idx += stride) {
    int i = idx & 7, lane = (idx>>3)&63, kt = idx>>9;
    int m = lane&15;
    int k = kt*32 + (lane>>4)*8 + i;
    float v = 0.f;
    if (m < 2) {
      if (k < 64) v = outw[m*64 + k];
      else if (k == 64) v = outb[m];
    }
    wo[idx] = (f16)v;
  }
}

// ---------------- quad-split MFMA LSTM: 4 waves/SIMD ----------------
// block = 1024 thr (16 waves = 4 quads), grid = 256, ~158 KB LDS, 16 waves/CU.
// Quad owns 32 cols (two 16-col col-sets). sub = wv&3: subs 0,1 = layer-0
// waves (rt-halves 0-7 / 8-15); subs 2,3 = layer-1 waves (same rt split),
// skewed one timestep. Same total work as R14, half per wave -> 4 waves/SIMD
// hide latency. Encoder phase = read-stage | barrier | compute+write | barrier
// (two B-waves share the in-place h1 stage; all-reads-before-all-writes makes
// that safe). Decoder: 4-way split (colset x rt-half), h1 double-buffered
// (s1b <-> dead h0buf), one barrier/step; both waves of a colset redo the
// cheap out-proj so x-feedback is local.
__global__ __launch_bounds__(1024, 4)
void lstm_mfma(const float* __restrict__ obs, char* __restrict__ ws, float* __restrict__ out)
{
  __shared__ __align__(16) f16   lw[18432];          // 36 KB: L0 (then dec) hh+aug pack
  __shared__ __align__(16) f16   lw1[32768];         // 64 KB: L1 cat pack
  __shared__ __align__(16) float lb1[256];           // 1 KB (gate-grouped, prescaled)
  __shared__ __align__(16) f16   lout[1536];         // 3 KB
  __shared__ __align__(16) f16   h0buf[4][2][2304];  // 36 KB: per-quad dbuf h0 / c-handoff / dec h1 buf0
  __shared__ __align__(16) f16   s1b[4][2304];       // 18 KB: per-quad h1 stage / dec h1 buf1

  const int tid  = threadIdx.x;
  const int wv   = tid >> 6;
  const int lane = tid & 63;
  const int grp  = wv >> 2;      // quad-group 0..3
  const int sub  = wv & 3;       // 0,1 = layer0 (rt-half 0,1); 2,3 = layer1
  const int role = sub >> 1;
  const int rh   = sub & 1;
  const int R    = rh*8;
  const int n    = lane & 15;
  const int quad = lane >> 4;
  const int e0   = blockIdx.x*128 + grp*32;
  const size_t bn  = (size_t)(e0 + n);        // col-set 1
  const size_t bn2 = (size_t)(e0 + 16 + n);   // col-set 2

  // ---- stage weights to LDS ----
  {
    uint4* d = (uint4*)lw;
    const uint4* s = (const uint4*)(ws + OFF_W0A);
    for (int i = tid; i < 2304; i += 1024) d[i] = s[i];
    uint4* d1 = (uint4*)lw1;
    const uint4* s1g = (const uint4*)(ws + OFF_W1);
    #pragma unroll
    for (int i = 0; i < 4; ++i) d1[tid + 1024*i] = s1g[tid + 1024*i];   // full 64 KB
    if (tid < 64)  ((uint4*)lb1)[tid] = ((const uint4*)(ws + OFF_B1))[tid];
    if (tid < 192) ((uint4*)lout)[tid] = ((const uint4*)(ws + OFF_OUT))[tid];
    uint4 z = {0,0,0,0};
    uint4* zp = (uint4*)&h0buf[0][0][0];
    for (int i = tid; i < 2304; i += 1024) zp[i] = z;
    uint4* zq = (uint4*)&s1b[0][0];
    for (int i = tid; i < 1152; i += 1024) zq[i] = z;
  }
  __syncthreads();

  const half8* AW  = (const half8*)lw;          // hh frags: [(rt*2+kt)*64 + lane]
  const half8* AWX = (const half8*)(lw + 16384);// aug-compact: [rt*16 + n]
  const half8* GA  = (const half8*)lw1;         // L1 frags: [(rt*4+kt)*64 + lane]
  const half8* LO  = (const half8*)lout;
  f16* s1 = &s1b[grp][0];

  float ccA[8], ccB[8];                         // c-state for this wave's 8 rts
  #pragma unroll
  for (int q = 0; q < 8; ++q) { ccA[q] = 0.f; ccB[q] = 0.f; }

  const int brd  = n*72 + quad*8;          // B-frag read (set 1), +32 for k hi
  const int brd2 = (n+16)*72 + quad*8;     // B-frag read (set 2)
  const int hwAw = n*72 + quad*16 + R;     // h write (set 1, this rt-half)
  const int hwBw = (n+16)*72 + quad*16 + R;// h write (set 2)

  // obs software pipeline (layer-0 waves; both subs load the same cols)
  float2 xvA, xvB;
  if (role == 0) {
    xvA = *(const float2*)(obs + (bn *TOBS + 0)*2);
    xvB = *(const float2*)(obs + (bn2*TOBS + 0)*2);
  }

  // ===================== pipelined encoder =====================
  for (int t = 0; t <= TOBS; ++t) {
    half8 hb0, hb1, hb0b, hb1b;               // A-wave reads
    half8 g0, g1, g2, g3, g0b, g1b, g2b, g3b; // B-wave reads
    half8 bx = (half8)(f16)0, bx2 = (half8)(f16)0;
    float2 xA1, xB1;
    // ---- read stage ----
    if (role == 0) {
      if (t < TOBS) {
        xA1 = make_float2(0.f,0.f); xB1 = make_float2(0.f,0.f);
        if (t+1 < TOBS) {
          xA1 = *(const float2*)(obs + (bn *TOBS + t+1)*2);
          xB1 = *(const float2*)(obs + (bn2*TOBS + t+1)*2);
        }
        if (quad == 0) {
          bx[0]  = (f16)xvA.x; bx[1]  = (f16)xvA.y; bx[2]  = (f16)1.0f;
          bx2[0] = (f16)xvB.x; bx2[1] = (f16)xvB.y; bx2[2] = (f16)1.0f;
        }
        const f16* rb = &h0buf[grp][(t&1)^1][0];
        hb0  = *(const half8*)(rb + brd);
        hb1  = *(const half8*)(rb + brd + 32);
        hb0b = *(const half8*)(rb + brd2);
        hb1b = *(const half8*)(rb + brd2 + 32);
      }
    } else {
      if (t >= 1) {
        const f16* gb = &h0buf[grp][(t&1)^1][0];
        g0  = *(const half8*)(gb + brd);
        g1  = *(const half8*)(gb + brd + 32);
        g2  = *(const half8*)(s1 + brd);
        g3  = *(const half8*)(s1 + brd + 32);
        g0b = *(const half8*)(gb + brd2);
        g1b = *(const half8*)(gb + brd2 + 32);
        g2b = *(const half8*)(s1 + brd2);
        g3b = *(const half8*)(s1 + brd2 + 32);
      }
    }
    __syncthreads();
    // ---- compute + write stage ----
    if (role == 0) {
      if (t < TOBS) {
        f16* wb = &h0buf[grp][(t&1)][0];
        half8 hvA, hvB;
        #pragma unroll
        for (int r = 0; r < 8; ++r) {
          const int rt = R + r;
          const half8 wA0 = AW[(rt*2+0)*64 + lane];
          const half8 wA1 = AW[(rt*2+1)*64 + lane];
          const half8 wAX = AWX[rt*16 + n];
          f32x4 a = {0.f,0.f,0.f,0.f};
          a = MFMA(wA0, hb0, a); a = MFMA(wA1, hb1, a); a = MFMA(wAX, bx, a);
          f32x4 a2 = {0.f,0.f,0.f,0.f};
          a2 = MFMA(wA0, hb0b, a2); a2 = MFMA(wA1, hb1b, a2); a2 = MFMA(wAX, bx2, a2);
          hvA[r] = (f16)gate_h(a,  ccA[r]);
          hvB[r] = (f16)gate_h(a2, ccB[r]);
        }
        *(half8*)(wb + hwAw) = hvA;
        *(half8*)(wb + hwBw) = hvB;
        xvA = xA1; xvB = xB1;
      }
    } else {
      if (t >= 1) {
        half8 hvA, hvB;
        #pragma unroll
        for (int r = 0; r < 8; ++r) {
          const int rt = R + r;
          const half8 w0_ = GA[(rt*4+0)*64 + lane];
          const half8 w1_ = GA[(rt*4+1)*64 + lane];
          const half8 w2_ = GA[(rt*4+2)*64 + lane];
          const half8 w3_ = GA[(rt*4+3)*64 + lane];
          const f32x4 bz = *(const f32x4*)(lb1 + rt*16 + quad*4);
          f32x4 a = bz;
          a = MFMA(w0_, g0, a); a = MFMA(w1_, g1, a);
          a = MFMA(w2_, g2, a); a = MFMA(w3_, g3, a);
          f32x4 a2 = bz;
          a2 = MFMA(w0_, g0b, a2); a2 = MFMA(w1_, g1b, a2);
          a2 = MFMA(w2_, g2b, a2); a2 = MFMA(w3_, g3b, a2);
          hvA[r] = (f16)gate_h(a,  ccA[r]);
          hvB[r] = (f16)gate_h(a2, ccB[r]);
        }
        *(half8*)(s1 + hwAw) = hvA;
        *(half8*)(s1 + hwBw) = hvB;
      }
    }
    __syncthreads();
  }

  // ---- decoder prep: weight swap + B-waves publish c1 to LDS ----
  {
    uint4* d = (uint4*)lw;
    const uint4* s = (const uint4*)(ws + OFF_WDA);
    for (int i = tid; i < 2304; i += 1024) d[i] = s[i];
    if (role == 1) {
      float* ctr = (float*)&h0buf[grp][0][0];   // h0buf dead after encoder
      #pragma unroll
      for (int r = 0; r < 8; ++r) {
        ctr[(0*16 + R + r)*64 + lane] = ccA[r];
        ctr[(1*16 + R + r)*64 + lane] = ccB[r];
      }
    }
  }
  __syncthreads();

  // ===================== 4-way split decoder =====================
  {
    const int cs  = sub >> 1;      // colset this wave decodes
    const int rhD = sub & 1;
    const int RD  = rhD*8;
    float cdec[8];
    {
      const float* ctr = (const float*)&h0buf[grp][0][0];
      #pragma unroll
      for (int r = 0; r < 8; ++r) cdec[r] = ctr[(cs*16 + RD + r)*64 + lane];
    }
    __syncthreads();   // protect c-scratch from step-0 h-writes into h0buf

    const int    brdD = cs ? brd2 : brd;
    const int    hwDw = (cs ? (n+16)*72 : n*72) + quad*16 + RD;
    const size_t bnD  = (size_t)(e0 + cs*16 + n);

    float x0, x1;
    {
      const float2 xd = *(const float2*)(obs + (bnD*TOBS + (TOBS-1))*2);
      x0 = xd.x; x1 = xd.y;
    }
    half8 ob1 = (half8)(f16)0;
    if (quad == 0) ob1[0] = (f16)1.0f;   // constant-1 B frag for out_b

    f16* buf0 = (f16*)&h0buf[grp][0][0];  // write target for even p
    f16* buf1 = s1;                       // holds initial h1; target for odd p

    for (int p = 0; p < TPRED; ++p) {
      f16*       wr = (p & 1) ? buf1 : buf0;
      const f16* rd = (p & 1) ? buf0 : buf1;

      half8 bx = (half8)(f16)0;
      if (quad == 0) { bx[0] = (f16)x0; bx[1] = (f16)x1; bx[2] = (f16)1.0f; }

      const half8 hb0 = *(const half8*)(rd + brdD);
      const half8 hb1 = *(const half8*)(rd + brdD + 32);
      half8 hv;
      #pragma unroll
      for (int r = 0; r < 8; ++r) {
        const int rt = RD + r;
        f32x4 a = {0.f,0.f,0.f,0.f};
        a = MFMA(AW[(rt*2+0)*64 + lane], hb0, a);
        a = MFMA(AW[(rt*2+1)*64 + lane], hb1, a);
        a = MFMA(AWX[rt*16 + n],          bx,  a);
        hv[r] = (f16)gate_h(a, cdec[r]);
      }
      *(half8*)(wr + hwDw) = hv;
      __syncthreads();   // h1(p) complete across the two rt-half waves

      // out-proj (both waves of a colset compute; rh0 stores)
      const half8 nh0 = *(const half8*)(wr + brdD);
      const half8 nh1 = *(const half8*)(wr + brdD + 32);
      f32x4 oa = {0.f,0.f,0.f,0.f};
      oa = MFMA(LO[0*64 + lane], nh0, oa);
      oa = MFMA(LO[1*64 + lane], nh1, oa);
      oa = MFMA(LO[2*64 + lane], ob1, oa);

      if (lane < 16 && rhD == 0)
        *(float2*)(out + (bnD*TPRED + p)*2) = make_float2(oa[0], oa[1]);
      x0 = __shfl(oa[0], n, 64);
      x1 = __shfl(oa[1], n, 64);
    }
  }
}

// ---------------- naive fp32 fallback (only if ws too small) ----------------
__global__ void lstm_naive(const float* __restrict__ obs,
    const float* wih0, const float* whh0, const float* bih0, const float* bhh0,
    const float* wih1, const float* whh1, const float* bih1, const float* bhh1,
    const float* dwih, const float* dwhh, const float* dbih, const float* dbhh,
    const float* outw, const float* outb, float* __restrict__ out)
{
  const int b = blockIdx.x*blockDim.x + threadIdx.x;
  if (b >= BATCH) return;
  float h0[64], c0[64], h1[64], c1[64], t0[64], t1[64];
  for (int j=0;j<64;j++){ h0[j]=0.f; c0[j]=0.f; h1[j]=0.f; c1[j]=0.f; }
  for (int t=0;t<TOBS;t++){
    const float x0 = obs[((size_t)b*TOBS+t)*2], x1 = obs[((size_t)b*TOBS+t)*2+1];
    for (int j=0;j<64;j++){
      float zz[4];
      for (int g=0;g<4;g++){
        const int r = g*64+j;
        float acc = bih0[r]+bhh0[r] + wih0[r*2]*x0 + wih0[r*2+1]*x1;
        for (int k=0;k<64;k++) acc += whh0[r*64+k]*h0[k];
        zz[g]=acc;
      }
      const float ig=1.f/(1.f+expf(-zz[0])), fg=1.f/(1.f+expf(-zz[1]));
      const float gg=tanhf(zz[2]), og=1.f/(1.f+expf(-zz[3]));
      c0[j]=fg*c0[j]+ig*gg; t0[j]=og*tanhf(c0[j]);
    }
    for (int j=0;j<64;j++){
      float zz[4];
      for (int g=0;g<4;g++){
        const int r = g*64+j;
        float acc = bih1[r]+bhh1[r];
        for (int k=0;k<64;k++) acc += wih1[r*64+k]*t0[k] + whh1[r*64+k]*h1[k];
        zz[g]=acc;
      }
      const float ig=1.f/(1.f+expf(-zz[0])), fg=1.f/(1.f+expf(-zz[1]));
      const float gg=tanhf(zz[2]), og=1.f/(1.f+expf(-zz[3]));
      c1[j]=fg*c1[j]+ig*gg; t1[j]=og*tanhf(c1[j]);
    }
    for (int j=0;j<64;j++){ h0[j]=t0[j]; h1[j]=t1[j]; }
  }
  float x0 = obs[((size_t)b*TOBS+19)*2], x1 = obs[((size_t)b*TOBS+19)*2+1];
  for (int p=0;p<TPRED;p++){
    for (int j=0;j<64;j++){
      float zz[4];
      for (int g=0;g<4;g++){
        const int r = g*64+j;
        float acc = dbih[r]+dbhh[r] + dwih[r*2]*x0 + dwih[r*2+1]*x1;
        for (int k=0;k<64;k++) acc += dwhh[r*64+k]*h1[k];
        zz[g]=acc;
      }
      const float ig=1.f/(1.f+expf(-zz[0])), fg=1.f/(1.f+expf(-zz[1]));
      const float gg=tanhf(zz[2]), og=1.f/(1.f+expf(-zz[3]));
      c1[j]=fg*c1[j]+ig*gg; t1[j]=og*tanhf(c1[j]);
    }
    for (int j=0;j<64;j++) h1[j]=t1[j];
    float o0=outb[0], o1=outb[1];
    for (int k=0;k<64;k++){ o0+=outw[k]*h1[k]; o1+=outw[64+k]*h1[k]; }
    out[((size_t)b*TPRED+p)*2]=o0; out[((size_t)b*TPRED+p)*2+1]=o1;
    x0=o0; x1=o1;
  }
}

extern "C" void kernel_launch(void* const* d_in, const int* in_sizes, int n_in,
                              void* d_out, int out_size, void* d_ws, size_t ws_size,
                              hipStream_t stream)
{
  const float* obs  = (const float*)d_in[0];
  const float* wih0 = (const float*)d_in[1];
  const float* whh0 = (const float*)d_in[2];
  const float* bih0 = (const float*)d_in[3];
  const float* bhh0 = (const float*)d_in[4];
  const float* wih1 = (const float*)d_in[5];
  const float* whh1 = (const float*)d_in[6];
  const float* bih1 = (const float*)d_in[7];
  const float* bhh1 = (const float*)d_in[8];
  const float* dwih = (const float*)d_in[9];
  const float* dwhh = (const float*)d_in[10];
  const float* dbih = (const float*)d_in[11];
  const float* dbhh = (const float*)d_in[12];
  const float* outw = (const float*)d_in[13];
  const float* outb = (const float*)d_in[14];
  float* outp = (float*)d_out;

  if (ws_size >= WS_NEED) {
    char* ws = (char*)d_ws;
    prep_pack<<<64, 256, 0, stream>>>(wih0, whh0, bih0, bhh0, wih1, whh1, bih1, bhh1,
                                      dwih, dwhh, dbih, dbhh, outw, outb, ws);
    lstm_mfma<<<256, 1024, 0, stream>>>(obs, ws, outp);
  } else {
    lstm_naive<<<(BATCH+255)/256, 256, 0, stream>>>(obs, wih0, whh0, bih0, bhh0,
        wih1, whh1, bih1, bhh1, dwih, dwhh, dbih, dbhh, outw, outb, outp);
  }
}

// Round 18
// 222.942 us; speedup vs baseline: 1.3557x; 1.3557x over previous
//
#include <hip/hip_runtime.h>
#include <math.h>

#define BATCH 32768
#define TOBS  20
#define TPRED 12

typedef _Float16 f16;
typedef f16  half8 __attribute__((ext_vector_type(8)));
typedef float f32x4 __attribute__((ext_vector_type(4)));

#define LOG2E 1.44269504088896f
#define K2    2.88539008177793f   // 2*log2(e)

// ---------------- d_ws layout (bytes) ----------------
// Gate-grouped A-fragment packing (rt-contiguous j), EXP2-PRESCALED:
//   packed row r' = rt*16 + m  represents original row (m&3)*64 + (m>>2)*16 + rt
//   (lane quad Q's 4 acc regs = gates i,f,g,o of hidden unit j = Q*16 + rt)
//   Sigmoid-gate rows (i,f,o) are scaled by log2e, g-gate rows by 2*log2e, so
//   exp(-z) / exp(-2z) become raw v_exp_f32 (exp2) with free neg modifier.
//   frag f16 index = ((rt*KT + kt)*64 + lane)*8 + i
#define OFF_W0A  0u        // L0:  [Whh0 kt0,1 | aug-compact]  32768 + 4096 = 36864 B
#define OFF_WDA  36864u    // dec: same structure              36864 B
#define OFF_W1   73728u    // L1 cat [Wih1|Whh1], KT=4         65536 B
#define OFF_B1   139264u   // bias1 gate-grouped f32[256]      1024 B (prescaled)
#define OFF_OUT  140288u   // out-proj frags KT=3 (UNSCALED)   3072 B
#define WS_NEED  ((size_t)143360)

__device__ __forceinline__ float frcp(float x){
#if __has_builtin(__builtin_amdgcn_rcpf)
  return __builtin_amdgcn_rcpf(x);
#else
  return 1.0f/x;
#endif
}
__device__ __forceinline__ float fexp2(float x){
#if __has_builtin(__builtin_amdgcn_exp2f)
  return __builtin_amdgcn_exp2f(x);
#else
  return exp2f(x);
#endif
}
__device__ __forceinline__ f32x4 MFMA(half8 a, half8 b, f32x4 c){
  return __builtin_amdgcn_mfma_f32_16x16x32_f16(a, b, c, 0, 0, 0);
}
__device__ __forceinline__ int grow(int rt, int m){  // gate-grouped original row
  return (m&3)*64 + (m>>2)*16 + rt;
}
__device__ __forceinline__ float gsc(int m){         // per-row exp2 prescale
  return ((m&3)==2) ? (2.0f*LOG2E) : LOG2E;
}

// Merged-rcp gate math: a = (z'_i, z'_f, z''_g, z'_o) prescaled; c updated in
// true units; returns h. 5 exp2 + 3 rcp.
__device__ __forceinline__ float gate_h(const f32x4 a, float& c){
  const float ei = fexp2(-a[0]);
  const float ef = fexp2(-a[1]);
  const float eg = fexp2(-a[2]);
  const float eo = fexp2(-a[3]);
  const float fg  = frcp(1.0f + ef);
  const float rig = frcp((1.0f + ei)*(1.0f + eg));
  const float cn  = fg*c + (1.0f - eg)*rig;
  c = cn;
  const float ec = fexp2(cn * -K2);
  return (1.0f - ec) * frcp((1.0f + eo)*(1.0f + ec));
}

// ---------------- weight packing ----------------
__global__ void prep_pack(const float* __restrict__ wih0, const float* __restrict__ whh0,
                          const float* __restrict__ bih0, const float* __restrict__ bhh0,
                          const float* __restrict__ wih1, const float* __restrict__ whh1,
                          const float* __restrict__ bih1, const float* __restrict__ bhh1,
                          const float* __restrict__ dwih, const float* __restrict__ dwhh,
                          const float* __restrict__ dbih, const float* __restrict__ dbhh,
                          const float* __restrict__ outw, const float* __restrict__ outb,
                          char* __restrict__ ws)
{
  const int tid = blockIdx.x*blockDim.x + threadIdx.x;
  const int stride = gridDim.x*blockDim.x;

  f16* w0 = (f16*)(ws + OFF_W0A);
  f16* wd = (f16*)(ws + OFF_WDA);
  // hh frags (kt=0,1), prescaled
  for (int idx = tid; idx < 16384; idx += stride) {
    int i = idx & 7, lane = (idx>>3)&63, kt = (idx>>9)&1, rt = idx>>10;
    int m = lane&15;
    int row = grow(rt, m);
    int k   = kt*32 + (lane>>4)*8 + i;
    float s = gsc(m);
    w0[idx] = (f16)(whh0[row*64 + k]*s);
    wd[idx] = (f16)(dwhh[row*64 + k]*s);
  }
  // aug-compact (quad0 data only): [rt][m][8]: i=0->wih[:,0], 1->wih[:,1], 2->bias
  for (int idx = tid; idx < 2048; idx += stride) {
    int i = idx & 7, m = (idx>>3)&15, rt = idx>>7;
    int row = grow(rt, m);
    float s = gsc(m);
    float v0 = (i==0) ? wih0[row*2] : (i==1) ? wih0[row*2+1] : (i==2) ? (bih0[row]+bhh0[row]) : 0.f;
    float vd = (i==0) ? dwih[row*2] : (i==1) ? dwih[row*2+1] : (i==2) ? (dbih[row]+dbhh[row]) : 0.f;
    w0[16384 + idx] = (f16)(v0*s);
    wd[16384 + idx] = (f16)(vd*s);
  }
  // L1 cat pack, KT=4: k<64 -> Wih1, else Whh1 (prescaled)
  f16* w1 = (f16*)(ws + OFF_W1);
  for (int idx = tid; idx < 32768; idx += stride) {
    int i = idx & 7, lane = (idx>>3)&63, kt = (idx>>9)&3, rt = idx>>11;
    int m = lane&15;
    int row = grow(rt, m);
    int k   = kt*32 + (lane>>4)*8 + i;
    float s = gsc(m);
    w1[idx] = (f16)(((k < 64) ? wih1[row*64 + k] : whh1[row*64 + (k-64)])*s);
  }
  // bias1 gate-grouped, prescaled
  float* b1 = (float*)(ws + OFF_B1);
  for (int idx = tid; idx < 256; idx += stride) {
    int m = idx & 15, rt = idx >> 4;
    int row = grow(rt, m);
    b1[idx] = (bih1[row] + bhh1[row])*gsc(m);
  }
  // out-proj frags KT=3 (plain rows 0,1; k=64 -> out_b) -- UNSCALED
  f16* wo = (f16*)(ws + OFF_OUT);
  for (int idx = tid; idx < 1536; idx += stride) {
    int i = idx & 7, lane = (idx>>3)&63, kt = idx>>9;
    int m = lane&15;
    int k = kt*32 + (lane>>4)*8 + i;
    float v = 0.f;
    if (m < 2) {
      if (k < 64) v = outw[m*64 + k];
      else if (k == 64) v = outb[m];
    }
    wo[idx] = (f16)v;
  }
}

// ---------------- pair-pipelined MFMA LSTM, 32 cols/pair, split decoder -----
// block = 512 thr (8 waves = 4 pairs), grid = 256, ~158 KB LDS, 8 waves/CU.
// Encoder: pair owns 32 cols as two 16-col col-sets sharing A-fragment reads.
// Wave A: layer 0; wave B: layer 1 skewed one step; h0 double-buffered;
// one __syncthreads/phase. Decoder: B hands set-2 c1 to A; both waves decode
// 16 cols each, barrier-free. Gate math: exp2-prescaled weights + merged rcps
// (5 exp2 + 3 rcp / step), fused per-rt (tiny live set -- no spill).
// R13-R17 showed: flag-sync neutral, acc[16] batching spills (>=128-VGPR
// allocator ceiling), group-of-4 neutral, 16-wave TLP regresses (spill +
// barriers). This configuration is the measured optimum (163 us).
__global__ __launch_bounds__(512, 2)
void lstm_mfma(const float* __restrict__ obs, char* __restrict__ ws, float* __restrict__ out)
{
  __shared__ __align__(16) f16   lw[18432];          // 36 KB: L0 (then dec) hh+aug pack
  __shared__ __align__(16) f16   lw1[32768];         // 64 KB: L1 cat pack
  __shared__ __align__(16) float lb1[256];           // 1 KB (gate-grouped, prescaled)
  __shared__ __align__(16) f16   lout[1536];         // 3 KB
  __shared__ __align__(16) f16   h0buf[4][2][2304];  // 36 KB: per-pair dbuf h0 (reused for c handoff)
  __shared__ __align__(16) f16   s1b[4][2304];       // 18 KB: per-pair h1 stage

  const int tid  = threadIdx.x;
  const int wv   = tid >> 6;
  const int lane = tid & 63;
  const int pr   = wv >> 1;      // pair 0..3
  const int role = wv & 1;       // 0 = layer0 producer, 1 = layer1 consumer
  const int n    = lane & 15;
  const int quad = lane >> 4;
  const int e0   = blockIdx.x*128 + pr*32;
  const size_t bn  = (size_t)(e0 + n);        // col-set 1
  const size_t bn2 = (size_t)(e0 + 16 + n);   // col-set 2

  // ---- stage weights to LDS ----
  {
    uint4* d = (uint4*)lw;
    const uint4* s = (const uint4*)(ws + OFF_W0A);
    for (int i = tid; i < 2304; i += 512) d[i] = s[i];
    uint4* d1 = (uint4*)lw1;
    const uint4* s1g = (const uint4*)(ws + OFF_W1);
    #pragma unroll
    for (int i = 0; i < 8; ++i) d1[tid + 512*i] = s1g[tid + 512*i];   // full 64 KB
    if (tid < 64)  ((uint4*)lb1)[tid] = ((const uint4*)(ws + OFF_B1))[tid];
    if (tid < 192) ((uint4*)lout)[tid] = ((const uint4*)(ws + OFF_OUT))[tid];
    // zero h0buf (2304 uint4) + s1b (1152 uint4)
    uint4 z = {0,0,0,0};
    uint4* zp = (uint4*)&h0buf[0][0][0];
    for (int i = tid; i < 2304; i += 512) zp[i] = z;
    uint4* zq = (uint4*)&s1b[0][0];
    for (int i = tid; i < 1152; i += 512) zq[i] = z;
  }
  __syncthreads();

  const half8* AW  = (const half8*)lw;          // hh frags: [(rt*2+kt)*64 + lane]
  const half8* AWX = (const half8*)(lw + 16384);// aug-compact: [rt*16 + n]
  const half8* GA  = (const half8*)lw1;         // L1 frags: [(rt*4+kt)*64 + lane]
  const half8* LO  = (const half8*)lout;
  f16* s1 = &s1b[pr][0];

  float ccA[16], ccB[16];                       // c-state, col-sets 1 & 2
  #pragma unroll
  for (int q = 0; q < 16; ++q) { ccA[q] = 0.f; ccB[q] = 0.f; }

  const int brd  = n*72 + quad*8;          // B-frag read (set 1), +32 for k hi
  const int brd2 = (n+16)*72 + quad*8;     // B-frag read (set 2)
  const int hwA  = n*72 + quad*16;         // h write base set 1 (16 contiguous)
  const int hwB  = (n+16)*72 + quad*16;    // h write base set 2

  // obs software pipeline (role 0): both col-sets
  float2 xvA, xvB;
  if (role == 0) {
    xvA = *(const float2*)(obs + (bn *TOBS + 0)*2);
    xvB = *(const float2*)(obs + (bn2*TOBS + 0)*2);
  }

  // ===================== pipelined encoder =====================
  for (int t = 0; t <= TOBS; ++t) {
    if (role == 0) {
      if (t < TOBS) {
        float2 xA1 = make_float2(0.f,0.f), xB1 = make_float2(0.f,0.f);
        if (t+1 < TOBS) {
          xA1 = *(const float2*)(obs + (bn *TOBS + t+1)*2);
          xB1 = *(const float2*)(obs + (bn2*TOBS + t+1)*2);
        }
        half8 bx  = (half8)(f16)0;
        half8 bx2 = (half8)(f16)0;
        if (quad == 0) {
          bx[0]  = (f16)xvA.x; bx[1]  = (f16)xvA.y; bx[2]  = (f16)1.0f;
          bx2[0] = (f16)xvB.x; bx2[1] = (f16)xvB.y; bx2[2] = (f16)1.0f;
        }
        const f16* rb = &h0buf[pr][(t&1)^1][0];
        f16*       wb = &h0buf[pr][(t&1)][0];
        const half8 hb0  = *(const half8*)(rb + brd);
        const half8 hb1  = *(const half8*)(rb + brd + 32);
        const half8 hb0b = *(const half8*)(rb + brd2);
        const half8 hb1b = *(const half8*)(rb + brd2 + 32);
        half8 hvA0, hvA1, hvB0, hvB1;
        #pragma unroll
        for (int rt = 0; rt < 16; ++rt) {
          const half8 wA0 = AW[(rt*2+0)*64 + lane];
          const half8 wA1 = AW[(rt*2+1)*64 + lane];
          const half8 wAX = AWX[rt*16 + n];
          f32x4 a = {0.f,0.f,0.f,0.f};
          a = MFMA(wA0, hb0, a); a = MFMA(wA1, hb1, a); a = MFMA(wAX, bx, a);
          f32x4 a2 = {0.f,0.f,0.f,0.f};
          a2 = MFMA(wA0, hb0b, a2); a2 = MFMA(wA1, hb1b, a2); a2 = MFMA(wAX, bx2, a2);
          {
            const f16 h = (f16)gate_h(a, ccA[rt]);
            if (rt < 8) hvA0[rt] = h; else hvA1[rt-8] = h;
          }
          {
            const f16 h = (f16)gate_h(a2, ccB[rt]);
            if (rt < 8) hvB0[rt] = h; else hvB1[rt-8] = h;
          }
        }
        *(half8*)(wb + hwA)     = hvA0;
        *(half8*)(wb + hwA + 8) = hvA1;
        *(half8*)(wb + hwB)     = hvB0;
        *(half8*)(wb + hwB + 8) = hvB1;
        xvA = xA1; xvB = xB1;
      }
    } else {
      if (t >= 1) {
        const f16* gb = &h0buf[pr][(t&1)^1][0];
        const half8 g0  = *(const half8*)(gb + brd);
        const half8 g1  = *(const half8*)(gb + brd + 32);
        const half8 g2  = *(const half8*)(s1 + brd);
        const half8 g3  = *(const half8*)(s1 + brd + 32);
        const half8 g0b = *(const half8*)(gb + brd2);
        const half8 g1b = *(const half8*)(gb + brd2 + 32);
        const half8 g2b = *(const half8*)(s1 + brd2);
        const half8 g3b = *(const half8*)(s1 + brd2 + 32);
        half8 hvA0, hvA1, hvB0, hvB1;
        #pragma unroll
        for (int rt = 0; rt < 16; ++rt) {
          const half8 w0_ = GA[(rt*4+0)*64 + lane];
          const half8 w1_ = GA[(rt*4+1)*64 + lane];
          const half8 w2_ = GA[(rt*4+2)*64 + lane];
          const half8 w3_ = GA[(rt*4+3)*64 + lane];
          const f32x4 bz = *(const f32x4*)(lb1 + rt*16 + quad*4);
          f32x4 a = bz;
          a = MFMA(w0_, g0, a); a = MFMA(w1_, g1, a);
          a = MFMA(w2_, g2, a); a = MFMA(w3_, g3, a);
          f32x4 a2 = bz;
          a2 = MFMA(w0_, g0b, a2); a2 = MFMA(w1_, g1b, a2);
          a2 = MFMA(w2_, g2b, a2); a2 = MFMA(w3_, g3b, a2);
          {
            const f16 h = (f16)gate_h(a, ccA[rt]);
            if (rt < 8) hvA0[rt] = h; else hvA1[rt-8] = h;
          }
          {
            const f16 h = (f16)gate_h(a2, ccB[rt]);
            if (rt < 8) hvB0[rt] = h; else hvB1[rt-8] = h;
          }
        }
        *(half8*)(s1 + hwA)     = hvA0;
        *(half8*)(s1 + hwA + 8) = hvA1;
        *(half8*)(s1 + hwB)     = hvB0;
        *(half8*)(s1 + hwB + 8) = hvB1;
      }
    }
    __syncthreads();
  }

  // ---- decoder prep: weight swap + B hands set-2 c1 to partner A ----
  {
    uint4* d = (uint4*)lw;
    const uint4* s = (const uint4*)(ws + OFF_WDA);
    for (int i = tid; i < 2304; i += 512) d[i] = s[i];
    if (role == 1) {
      float* ctr = (float*)&h0buf[pr][0][0];   // h0buf dead after encoder
      #pragma unroll
      for (int q = 0; q < 4; ++q)
        *(f32x4*)(ctr + lane*16 + q*4) = *(const f32x4*)(&ccB[q*4]);
    }
  }
  __syncthreads();

  // ===================== split decoder (both waves, barrier-free) ==========
  {
    // B keeps col-set 1 (its ccA); A takes col-set 2 (c from handoff).
    float cdec[16];
    if (role == 1) {
      #pragma unroll
      for (int q = 0; q < 16; ++q) cdec[q] = ccA[q];
    } else {
      const float* ctr = (const float*)&h0buf[pr][0][0];
      #pragma unroll
      for (int q = 0; q < 4; ++q)
        *(f32x4*)(&cdec[q*4]) = *(const f32x4*)(ctr + lane*16 + q*4);
    }
    const int    brdD = role ? brd : brd2;
    const int    hwD  = role ? hwA : hwB;
    const size_t bnD  = role ? bn  : bn2;

    float x0, x1;
    {
      const float2 xd = *(const float2*)(obs + (bnD*TOBS + (TOBS-1))*2);
      x0 = xd.x; x1 = xd.y;
    }
    half8 ob1 = (half8)(f16)0;
    if (quad == 0) ob1[0] = (f16)1.0f;   // constant-1 B frag for out_b

    for (int p = 0; p < TPRED; ++p) {
      half8 bx = (half8)(f16)0;
      if (quad == 0) { bx[0] = (f16)x0; bx[1] = (f16)x1; bx[2] = (f16)1.0f; }

      const half8 hb0 = *(const half8*)(s1 + brdD);
      const half8 hb1 = *(const half8*)(s1 + brdD + 32);
      half8 hv0, hv1;
      #pragma unroll
      for (int rt = 0; rt < 16; ++rt) {
        f32x4 a = {0.f,0.f,0.f,0.f};
        a = MFMA(AW[(rt*2+0)*64 + lane], hb0, a);
        a = MFMA(AW[(rt*2+1)*64 + lane], hb1, a);
        a = MFMA(AWX[rt*16 + n],          bx,  a);
        const f16 h = (f16)gate_h(a, cdec[rt]);
        if (rt < 8) hv0[rt] = h; else hv1[rt-8] = h;
      }
      *(half8*)(s1 + hwD)     = hv0;
      *(half8*)(s1 + hwD + 8) = hv1;

      // out-proj: o = out_w*h_new + out_b  (rows 0,1 of a 16-row tile)
      const half8 nh0 = *(const half8*)(s1 + brdD);
      const half8 nh1 = *(const half8*)(s1 + brdD + 32);
      f32x4 oa = {0.f,0.f,0.f,0.f};
      oa = MFMA(LO[0*64 + lane], nh0, oa);
      oa = MFMA(LO[1*64 + lane], nh1, oa);
      oa = MFMA(LO[2*64 + lane], ob1, oa);

      if (lane < 16)
        *(float2*)(out + (bnD*TPRED + p)*2) = make_float2(oa[0], oa[1]);
      x0 = __shfl(oa[0], n, 64);
      x1 = __shfl(oa[1], n, 64);
    }
  }
}

// ---------------- naive fp32 fallback (only if ws too small) ----------------
__global__ void lstm_naive(const float* __restrict__ obs,
    const float* wih0, const float* whh0, const float* bih0, const float* bhh0,
    const float* wih1, const float* whh1, const float* bih1, const float* bhh1,
    const float* dwih, const float* dwhh, const float* dbih, const float* dbhh,
    const float* outw, const float* outb, float* __restrict__ out)
{
  const int b = blockIdx.x*blockDim.x + threadIdx.x;
  if (b >= BATCH) return;
  float h0[64], c0[64], h1[64], c1[64], t0[64], t1[64];
  for (int j=0;j<64;j++){ h0[j]=0.f; c0[j]=0.f; h1[j]=0.f; c1[j]=0.f; }
  for (int t=0;t<TOBS;t++){
    const float x0 = obs[((size_t)b*TOBS+t)*2], x1 = obs[((size_t)b*TOBS+t)*2+1];
    for (int j=0;j<64;j++){
      float zz[4];
      for (int g=0;g<4;g++){
        const int r = g*64+j;
        float acc = bih0[r]+bhh0[r] + wih0[r*2]*x0 + wih0[r*2+1]*x1;
        for (int k=0;k<64;k++) acc += whh0[r*64+k]*h0[k];
        zz[g]=acc;
      }
      const float ig=1.f/(1.f+expf(-zz[0])), fg=1.f/(1.f+expf(-zz[1]));
      const float gg=tanhf(zz[2]), og=1.f/(1.f+expf(-zz[3]));
      c0[j]=fg*c0[j]+ig*gg; t0[j]=og*tanhf(c0[j]);
    }
    for (int j=0;j<64;j++){
      float zz[4];
      for (int g=0;g<4;g++){
        const int r = g*64+j;
        float acc = bih1[r]+bhh1[r];
        for (int k=0;k<64;k++) acc += wih1[r*64+k]*t0[k] + whh1[r*64+k]*h1[k];
        zz[g]=acc;
      }
      const float ig=1.f/(1.f+expf(-zz[0])), fg=1.f/(1.f+expf(-zz[1]));
      const float gg=tanhf(zz[2]), og=1.f/(1.f+expf(-zz[3]));
      c1[j]=fg*c1[j]+ig*gg; t1[j]=og*tanhf(c1[j]);
    }
    for (int j=0;j<64;j++){ h0[j]=t0[j]; h1[j]=t1[j]; }
  }
  float x0 = obs[((size_t)b*TOBS+19)*2], x1 = obs[((size_t)b*TOBS+19)*2+1];
  for (int p=0;p<TPRED;p++){
    for (int j=0;j<64;j++){
      float zz[4];
      for (int g=0;g<4;g++){
        const int r = g*64+j;
        float acc = dbih[r]+dbhh[r] + dwih[r*2]*x0 + dwih[r*2+1]*x1;
        for (int k=0;k<64;k++) acc += dwhh[r*64+k]*h1[k];
        zz[g]=acc;
      }
      const float ig=1.f/(1.f+expf(-zz[0])), fg=1.f/(1.f+expf(-zz[1]));
      const float gg=tanhf(zz[2]), og=1.f/(1.f+expf(-zz[3]));
      c1[j]=fg*c1[j]+ig*gg; t1[j]=og*tanhf(c1[j]);
    }
    for (int j=0;j<64;j++) h1[j]=t1[j];
    float o0=outb[0], o1=outb[1];
    for (int k=0;k<64;k++){ o0+=outw[k]*h1[k]; o1+=outw[64+k]*h1[k]; }
    out[((size_t)b*TPRED+p)*2]=o0; out[((size_t)b*TPRED+p)*2+1]=o1;
    x0=o0; x1=o1;
  }
}

extern "C" void kernel_launch(void* const* d_in, const int* in_sizes, int n_in,
                              void* d_out, int out_size, void* d_ws, size_t ws_size,
                              hipStream_t stream)
{
  const float* obs  = (const float*)d_in[0];
  const float* wih0 = (const float*)d_in[1];
  const float* whh0 = (const float*)d_in[2];
  const float* bih0 = (const float*)d_in[3];
  const float* bhh0 = (const float*)d_in[4];
  const float* wih1 = (const float*)d_in[5];
  const float* whh1 = (const float*)d_in[6];
  const float* bih1 = (const float*)d_in[7];
  const float* bhh1 = (const float*)d_in[8];
  const float* dwih = (const float*)d_in[9];
  const float* dwhh = (const float*)d_in[10];
  const float* dbih = (const float*)d_in[11];
  const float* dbhh = (const float*)d_in[12];
  const float* outw = (const float*)d_in[13];
  const float* outb = (const float*)d_in[14];
  float* outp = (float*)d_out;

  if (ws_size >= WS_NEED) {
    char* ws = (char*)d_ws;
    prep_pack<<<64, 256, 0, stream>>>(wih0, whh0, bih0, bhh0, wih1, whh1, bih1, bhh1,
                                      dwih, dwhh, dbih, dbhh, outw, outb, ws);
    lstm_mfma<<<256, 512, 0, stream>>>(obs, ws, outp);
  } else {
    lstm_naive<<<(BATCH+255)/256, 256, 0, stream>>>(obs, wih0, whh0, bih0, bhh0,
        wih1, whh1, bih1, bhh1, dwih, dwhh, dbih, dbhh, outw, outb, outp);
  }
}